// Round 6
// baseline (796.845 us; speedup 1.0000x reference)
//
#include <hip/hip_runtime.h>
#include <hip/hip_bf16.h>
#include <stdint.h>

// AttentionGate: out = softmax((q@Wq+bq)(k@Wk+bk)^T / sqrt(512)) @ (v@Wv+bv)
// B=8, S=2048, d=512. Round 6:
//  - attn: NO K/V LDS staging (zero data reuse -> LDS round-trip was pure
//    overhead). Direct global->VGPR b128 frag loads (full-cacheline patterns),
//    32 q-rows per wave (halves per-FLOP load traffic), zero barriers ->
//    unbounded compiler prefetch. 2 fat waves/CU (reg-bound by design).
//  - proj: A fp32 load pipelined one iter ahead (HBM latency hidden behind
//    MFMAs); B-DMA after barrier as in R5.
//  - linear softmax (bounded scores) kept from R3.
// ws: WT 1.5MB | qp 16MB | kp 16MB | vpT 16MB (blocked [b][kb][d][32]).

typedef __attribute__((ext_vector_type(8))) short short8;
typedef __attribute__((ext_vector_type(4))) float floatx4;

__device__ __forceinline__ unsigned short f2bf(float f) {
    union { float f; uint32_t u; } v; v.f = f;
    uint32_t u = v.u;
    return (unsigned short)((u + 0x7FFF + ((u >> 16) & 1)) >> 16);  // RNE
}

// async 16B/lane global->LDS DMA. LDS dest = wave-uniform base + lane*16.
#define ASYNC16(g, l)                                                          \
    __builtin_amdgcn_global_load_lds(                                          \
        (const __attribute__((address_space(1))) unsigned int*)(g),            \
        (__attribute__((address_space(3))) unsigned int*)(l), 16, 0, 0)

// ---------------- kernel 0: W -> WT bf16 (WT[z][n][k] = W_z[k][n]) -------------
__global__ void wt_kernel(const float* __restrict__ Wq, const float* __restrict__ Wk,
                          const float* __restrict__ Wv, unsigned short* __restrict__ WT) {
    __shared__ float t[64][65];
    const int z = blockIdx.z;
    const float* W = (z == 0) ? Wq : ((z == 1) ? Wk : Wv);
    const int n0 = blockIdx.x * 64, k0 = blockIdx.y * 64;
    const int tx = threadIdx.x & 63, ty = threadIdx.x >> 6;
#pragma unroll
    for (int i = ty; i < 64; i += 4) t[i][tx] = W[(size_t)(k0 + i) * 512 + n0 + tx];
    __syncthreads();
#pragma unroll
    for (int i = ty; i < 64; i += 4)
        WT[(size_t)z * 262144 + (size_t)(n0 + i) * 512 + k0 + tx] = f2bf(t[tx][i]);
}

// ---------------- kernel 1: projections (LDS-staged GEMM, pipelined) -----------
// grid (256,1,3), block 256 (4 waves). Block: 64 rows x FULL N=512; wave owns
// 128 cols (4x8 frags). 32-k chunks dbuf; B via global_load_lds post-barrier;
// A fp32 loaded ONE ITER EARLY into regs, converted+ds_written post-barrier
// (HBM latency overlaps a full compute phase). LDS 72KB -> 2 blocks/CU.
__global__ __launch_bounds__(256, 2) void proj_kernel(
    const float* __restrict__ q, const float* __restrict__ k, const float* __restrict__ v,
    const float* __restrict__ bq, const float* __restrict__ bk, const float* __restrict__ bv,
    const unsigned short* __restrict__ WT,
    unsigned short* __restrict__ qp, unsigned short* __restrict__ kp,
    unsigned short* __restrict__ vpT)
{
    __shared__ __align__(16) unsigned short At[2][64][32];
    __shared__ __align__(16) unsigned short Bt[2][512][32];

    const int z = blockIdx.z;
    const int lane = threadIdx.x & 63;
    const int wave = threadIdx.x >> 6;
    const int col = lane & 15;
    const int quad = lane >> 4;

    const float* A = (z == 0) ? q : ((z == 1) ? k : v);
    const float* bias = (z == 0) ? bq : ((z == 1) ? bk : bv);
    const unsigned short* W = WT + (size_t)z * 262144;

    const int m0 = blockIdx.x * 64;
    const int n0w = wave * 128;
    const int arow = wave * 16 + (lane >> 2);            // A-stage row for this lane

    floatx4 acc[4][8];
#pragma unroll
    for (int mf = 0; mf < 4; ++mf)
#pragma unroll
        for (int nf = 0; nf < 8; ++nf) acc[mf][nf] = floatx4{0.f, 0.f, 0.f, 0.f};

    auto stageB = [&](int nb, int kc) {
#pragma unroll
        for (int jj = 0; jj < 8; ++jj) {
            const int j = wave * 8 + jj;
            const int row = j * 16 + (lane >> 2);
            const unsigned short* g =
                W + (size_t)row * 512 + kc * 32 + (((lane & 3) ^ (row & 3)) << 3);
            ASYNC16(g, &Bt[nb][j * 16][0]);
        }
    };
    auto loadA = [&](float4& f0, float4& f1, int kc) {
        const float* ap = A + (size_t)(m0 + arow) * 512 + kc * 32 + (lane & 3) * 8;
        f0 = *(const float4*)ap;
        f1 = *(const float4*)(ap + 4);
    };
    auto writeA = [&](int nb, const float4& f0, const float4& f1) {
        short8 t;
        t[0] = f2bf(f0.x); t[1] = f2bf(f0.y); t[2] = f2bf(f0.z); t[3] = f2bf(f0.w);
        t[4] = f2bf(f1.x); t[5] = f2bf(f1.y); t[6] = f2bf(f1.z); t[7] = f2bf(f1.w);
        *(short8*)&At[nb][arow][((lane & 3) ^ (arow & 3)) << 3] = t;
    };

    float4 ra0, ra1;
    stageB(0, 0);
    loadA(ra0, ra1, 0);
    writeA(0, ra0, ra1);          // one-time stall on load(0)
    loadA(ra0, ra1, 1);           // in flight across iter 0's compute

    for (int kc = 0; kc < 16; ++kc) {
        const int cur = kc & 1;
        __syncthreads();          // publishes buf `cur` (B-DMA + A-write drained)
        if (kc < 15) {
            stageB(cur ^ 1, kc + 1);       // DMA overlaps compute below
            writeA(cur ^ 1, ra0, ra1);     // ra = A(kc+1), loaded an iter ago
        }
        if (kc < 14) loadA(ra0, ra1, kc + 2);

        short8 a[4], bfr[8];
#pragma unroll
        for (int mf = 0; mf < 4; ++mf)
            a[mf] = *(const short8*)&At[cur][mf * 16 + col][(quad ^ (col & 3)) << 3];
#pragma unroll
        for (int nf = 0; nf < 8; ++nf)
            bfr[nf] = *(const short8*)&Bt[cur][n0w + nf * 16 + col][(quad ^ (col & 3)) << 3];
#pragma unroll
        for (int mf = 0; mf < 4; ++mf)
#pragma unroll
            for (int nf = 0; nf < 8; ++nf)
                acc[mf][nf] = __builtin_amdgcn_mfma_f32_16x16x32_bf16(a[mf], bfr[nf], acc[mf][nf], 0, 0, 0);
    }

    const float scale = (z == 0) ? 0.04419417382415922f : 1.0f;  // 1/sqrt(512) into qp
#pragma unroll
    for (int mf = 0; mf < 4; ++mf) {
#pragma unroll
        for (int nf = 0; nf < 8; ++nf) {
            const int n = n0w + nf * 16 + col;
            const float bn2 = bias[n];
            floatx4 c = acc[mf][nf];
            if (z < 2) {
                unsigned short* outp = (z == 0) ? qp : kp;
#pragma unroll
                for (int r = 0; r < 4; ++r) {
                    int row = m0 + mf * 16 + quad * 4 + r;
                    outp[(size_t)row * 512 + n] = f2bf((c[r] + bn2) * scale);
                }
            } else {
                // blocked vpT: [b][s>>5][d][s&31]; 4 consecutive keys per ushort4
                int row = m0 + mf * 16 + quad * 4;
                int bb = row >> 11;
                int s = row & 2047;
                ushort4 pk;
                pk.x = f2bf(c[0] + bn2); pk.y = f2bf(c[1] + bn2);
                pk.z = f2bf(c[2] + bn2); pk.w = f2bf(c[3] + bn2);
                *(ushort4*)(vpT + (((size_t)bb * 64 + (s >> 5)) * 512 + n) * 32 + (s & 31)) = pk;
            }
        }
    }
}

// ---------------- kernel 2: attention, direct-global, barrier-free -------------
// grid 256 x 128 threads (2 waves). Wave owns 32 q-rows (2 m-tiles):
//   aq resident (128 VGPR), O = 64 accvgpr tiles (256), plsum 8.
// Per 32-key iter: 32 K-frag + 32 V-frag direct b128 global loads (each pulls
// 16 full 64B lines), 128 MFMA, 16 exp, P via tiny per-wave Pbuf. No barriers.
__global__ __launch_bounds__(128, 1) void attn_kernel(
    const unsigned short* __restrict__ qp, const unsigned short* __restrict__ kp,
    const unsigned short* __restrict__ vpT, float* __restrict__ out)
{
    __shared__ __align__(16) unsigned short Pbuf[2][32][40];  // per-wave P (32q x 32k)

    const int lane = threadIdx.x & 63;
    const int w = threadIdx.x >> 6;
    const int col = lane & 15;
    const int quad = lane >> 4;
    const int b = blockIdx.x & 7;              // XCD-local batch
    const int qt = blockIdx.x >> 3;            // 0..31
    const int q0 = qt * 64 + w * 32;
    const size_t rowbase = (size_t)b * 2048 + q0;

    const unsigned short* kpb = kp + (size_t)b * 2048 * 512;
    const unsigned short* vpb = vpT + ((size_t)b << 20);   // [64][512][32] blocked

    // qp A-frags resident: 2 m-tiles x 16 k-steps
    short8 aq[2][16];
#pragma unroll
    for (int mt = 0; mt < 2; ++mt)
#pragma unroll
        for (int ks = 0; ks < 16; ++ks)
            aq[mt][ks] = *(const short8*)(qp + (rowbase + mt * 16 + col) * 512 + ks * 32 + quad * 8);

    floatx4 o[2][32];
#pragma unroll
    for (int mt = 0; mt < 2; ++mt)
#pragma unroll
        for (int dt = 0; dt < 32; ++dt) o[mt][dt] = floatx4{0.f, 0.f, 0.f, 0.f};
    float plsum[2][4] = {{0.f, 0.f, 0.f, 0.f}, {0.f, 0.f, 0.f, 0.f}};

    for (int kb = 0; kb < 64; ++kb) {
        const int key0 = kb * 32;
        const unsigned short* vtile = vpb + ((size_t)kb << 14);  // [512][32]

        // ---- S = qp @ kp^T (32 q x 32 keys), B-frags direct from global ----
        floatx4 s[2][2];
        s[0][0] = floatx4{0.f, 0.f, 0.f, 0.f}; s[0][1] = floatx4{0.f, 0.f, 0.f, 0.f};
        s[1][0] = floatx4{0.f, 0.f, 0.f, 0.f}; s[1][1] = floatx4{0.f, 0.f, 0.f, 0.f};
#pragma unroll
        for (int ks = 0; ks < 16; ++ks) {
            short8 b0 = *(const short8*)(kpb + (size_t)(key0 + col) * 512 + ks * 32 + quad * 8);
            short8 b1 = *(const short8*)(kpb + (size_t)(key0 + 16 + col) * 512 + ks * 32 + quad * 8);
            s[0][0] = __builtin_amdgcn_mfma_f32_16x16x32_bf16(aq[0][ks], b0, s[0][0], 0, 0, 0);
            s[1][0] = __builtin_amdgcn_mfma_f32_16x16x32_bf16(aq[1][ks], b0, s[1][0], 0, 0, 0);
            s[0][1] = __builtin_amdgcn_mfma_f32_16x16x32_bf16(aq[0][ks], b1, s[0][1], 0, 0, 0);
            s[1][1] = __builtin_amdgcn_mfma_f32_16x16x32_bf16(aq[1][ks], b1, s[1][1], 0, 0, 0);
        }

        // ---- linear softmax: p = exp(s), l per-lane; P -> per-wave Pbuf ----
#pragma unroll
        for (int mt = 0; mt < 2; ++mt)
#pragma unroll
            for (int r = 0; r < 4; ++r) {
                const float p0 = __expf(s[mt][0][r]);
                const float p1 = __expf(s[mt][1][r]);
                plsum[mt][r] += p0 + p1;
                Pbuf[w][mt * 16 + quad * 4 + r][col]      = f2bf(p0);
                Pbuf[w][mt * 16 + quad * 4 + r][16 + col] = f2bf(p1);
            }
        const short8 aP0 = *(const short8*)&Pbuf[w][col][quad * 8];
        const short8 aP1 = *(const short8*)&Pbuf[w][16 + col][quad * 8];

        // ---- O += P @ V, B-frags direct from blocked vpT (full lines) ----
#pragma unroll
        for (int dt = 0; dt < 32; ++dt) {
            short8 bv = *(const short8*)(vtile + (size_t)(dt * 16 + col) * 32 + quad * 8);
            o[0][dt] = __builtin_amdgcn_mfma_f32_16x16x32_bf16(aP0, bv, o[0][dt], 0, 0, 0);
            o[1][dt] = __builtin_amdgcn_mfma_f32_16x16x32_bf16(aP1, bv, o[1][dt], 0, 0, 0);
        }
    }

    // ---- epilogue: reduce l over the 16 cols, then O / l ----
    float l[2][4];
#pragma unroll
    for (int mt = 0; mt < 2; ++mt)
#pragma unroll
        for (int r = 0; r < 4; ++r) {
            float acc_s = plsum[mt][r];
#pragma unroll
            for (int off = 1; off <= 8; off <<= 1)
                acc_s += __shfl_xor(acc_s, off, 64);
            l[mt][r] = acc_s;
        }
#pragma unroll
    for (int mt = 0; mt < 2; ++mt)
#pragma unroll
        for (int dt = 0; dt < 32; ++dt)
#pragma unroll
            for (int r = 0; r < 4; ++r)
                out[(rowbase + mt * 16 + quad * 4 + r) * 512 + dt * 16 + col] =
                    o[mt][dt][r] / l[mt][r];
}

extern "C" void kernel_launch(void* const* d_in, const int* in_sizes, int n_in,
                              void* d_out, int out_size, void* d_ws, size_t ws_size,
                              hipStream_t stream) {
    const float* q  = (const float*)d_in[0];
    const float* k  = (const float*)d_in[1];
    const float* v  = (const float*)d_in[2];
    const float* Wq = (const float*)d_in[3];
    const float* bq = (const float*)d_in[4];
    const float* Wk = (const float*)d_in[5];
    const float* bk = (const float*)d_in[6];
    const float* Wv = (const float*)d_in[7];
    const float* bv = (const float*)d_in[8];
    float* out = (float*)d_out;

    unsigned short* WT  = (unsigned short*)d_ws;              // 3*512*512 bf16
    unsigned short* qp  = WT + (size_t)3 * 262144;            // 16384*512
    unsigned short* kp  = qp + (size_t)16384 * 512;
    unsigned short* vpT = kp + (size_t)16384 * 512;           // [8][64][512][32] blocked

    wt_kernel<<<dim3(8, 8, 3), 256, 0, stream>>>(Wq, Wk, Wv, WT);
    proj_kernel<<<dim3(256, 1, 3), 256, 0, stream>>>(q, k, v, bq, bk, bv, WT, qp, kp, vpT);
    attn_kernel<<<256, 128, 0, stream>>>(qp, kp, vpT, out);
}